// Round 11
// baseline (163.427 us; speedup 1.0000x reference)
//
#include <hip/hip_runtime.h>

// PreHTSK fused, MFMA edition v8 — 3 launches; NO mass atomics.
// gemm blocks store Spart[bt][ks] tiles (plain, deterministic), bump cnt[bt];
// the 16th block per bt sums the slices + affine constant -> out.
// out[b,o] = rstd[b]*(S+T) + Bb[o] - mur[b]*G[o]
//   S = sum_r frs[b,r] * sum_i X[b,i]*gamma[r*256+i]*W[o,r*256+i]
//   T = sum_r frs[b,r] * Wtail[r][o]
// LN closed-form: mu=(Sx+1)/D, E[f^2]=Q*(Sx2+1)/D, Q=sum frs^2 (sum frs = 1).

#define B_    2048
#define IN_   256
#define NR_   128
#define OUT_  64
#define D_    32896
#define XP_   32768
#define KSPLIT 16   // rule-groups; 8 rules per gemm block

typedef short s16x8 __attribute__((ext_vector_type(8)));
typedef float f32x4 __attribute__((ext_vector_type(4)));

__device__ __forceinline__ unsigned short bfc(float f) {
  union { float f; unsigned int u; } v; v.f = f;
  unsigned int r = (v.u + 0x7fffu + ((v.u >> 16) & 1u)) >> 16;  // RNE
  return (unsigned short)r;
}

__device__ __forceinline__ void gload_lds16(const void* g, void* l) {
  __builtin_amdgcn_global_load_lds(
      (const __attribute__((address_space(1))) void*)g,
      (__attribute__((address_space(3))) void*)l, 16, 0, 0);
}

// ================= Kernel A (512 blocks, 512 thr):
//   0..255   pack: r = bid>>1, ic-half = bid&1. Bpack fragments (bf16 gamma*W),
//            Gpart/Bpart partials ([o][1024] transposed), Wtail (half==1).
//   256..511 frs: firing levels + softmax + LN stats + X->bf16; zero cnt.
__global__ __launch_bounds__(512) void prep_frs_kernel(
    const float* __restrict__ X, const float* __restrict__ centers,
    const float* __restrict__ sigmas, const float* __restrict__ W,
    const float* __restrict__ gamma, const float* __restrict__ beta,
    unsigned short* __restrict__ Bpack, float* __restrict__ Gpart,
    float* __restrict__ Bpart, float* __restrict__ Wtail,
    float* __restrict__ frs, float* __restrict__ rstdO,
    float* __restrict__ murO, unsigned short* __restrict__ Xbf,
    int* __restrict__ cnt) {
  __shared__ float Wlds[64][68];      // pack path
  __shared__ float Xs[8][256];        // frs path
  __shared__ float pre[4][8][128];
  int tid = threadIdx.x;

  if (blockIdx.x < 256) {             // ---- pack path
    int r = blockIdx.x >> 1, half = blockIdx.x & 1;
    int lane = tid & 63, w = tid >> 6;
    int kcl = w & 1, ct = w >> 1;     // wave handles (k-half, col-tile)
    int o_f = ct * 16 + (lane & 15);
    if (half == 1 && tid < 64) {      // Wtail[r][o] (scattered, 64 loads)
      int d = XP_ + r;
      Wtail[r * 64 + tid] = W[(size_t)tid * D_ + d] * gamma[d];
    }
    for (int ici = 0; ici < 2; ici++) {
      int ic = half * 2 + ici;
      // coalesced: W[o][r*256+ic*64 .. +64) -> Wlds[o][0..64)
      for (int v = tid; v < 1024; v += 512) {
        int o = v >> 4, c4 = v & 15;
        float4 x = *(const float4*)&W[(size_t)o * D_ + r * 256 + ic * 64 + c4 * 4];
        *(float4*)&Wlds[o][c4 * 4] = x;
      }
      __syncthreads();
      int kc = ic * 2 + kcl;
      int il = kcl * 32 + (lane >> 4) * 8;
      int dg = r * 256 + ic * 64 + il;
      float4 g0  = *(const float4*)&gamma[dg];
      float4 g1  = *(const float4*)&gamma[dg + 4];
      float4 be0 = *(const float4*)&beta[dg];
      float4 be1 = *(const float4*)&beta[dg + 4];
      float4 w0 = *(const float4*)&Wlds[o_f][il];
      float4 w1 = *(const float4*)&Wlds[o_f][il + 4];
      unsigned int u[4];
      u[0] = bfc(w0.x * g0.x) | ((unsigned int)bfc(w0.y * g0.y) << 16);
      u[1] = bfc(w0.z * g0.z) | ((unsigned int)bfc(w0.w * g0.w) << 16);
      u[2] = bfc(w1.x * g1.x) | ((unsigned int)bfc(w1.y * g1.y) << 16);
      u[3] = bfc(w1.z * g1.z) | ((unsigned int)bfc(w1.w * g1.w) << 16);
      int rb = r * 8 + kc;
      *(uint4*)&Bpack[((size_t)(rb * 4 + ct) * 64 + lane) * 8] = make_uint4(u[0], u[1], u[2], u[3]);
      float gs = w0.x*g0.x + w0.y*g0.y + w0.z*g0.z + w0.w*g0.w
               + w1.x*g1.x + w1.y*g1.y + w1.z*g1.z + w1.w*g1.w;
      float bs = w0.x*be0.x + w0.y*be0.y + w0.z*be0.z + w0.w*be0.w
               + w1.x*be1.x + w1.y*be1.y + w1.z*be1.z + w1.w*be1.w;
      gs += __shfl_xor(gs, 16); gs += __shfl_xor(gs, 32);
      bs += __shfl_xor(bs, 16); bs += __shfl_xor(bs, 32);
      if ((lane >> 4) == 0) {         // transposed: [o][rb] for coalesced reduce
        Gpart[(size_t)o_f * 1024 + rb] = gs;
        Bpart[(size_t)o_f * 1024 + rb] = bs;
      }
      __syncthreads();
    }
    return;
  }

  // ---- frs path
  int bt = blockIdx.x - 256;          // 0..255
  int b0 = bt * 8;
  {
    if (tid == 0 && bt < 32) cnt[bt] = 0;   // zero gemm completion counters
    int row = tid >> 6, c4 = (tid & 63) * 4;
    float4 x = *(const float4*)&X[(size_t)(b0 + row) * 256 + c4];
    *(float4*)&Xs[row][c4] = x;
    uint2 p;
    p.x = bfc(x.x) | ((unsigned int)bfc(x.y) << 16);
    p.y = bfc(x.z) | ((unsigned int)bfc(x.w) << 16);
    *(uint2*)&Xbf[(size_t)(b0 + row) * 256 + c4] = p;
  }
  __syncthreads();
  int r = tid & 127, h = tid >> 7;
  float acc[8] = {0.f,0.f,0.f,0.f,0.f,0.f,0.f,0.f};
  int i0 = h * 64;
#pragma unroll 4
  for (int i = i0; i < i0 + 64; i++) {
    float sg = sigmas[i * NR_ + r];
    float c  = centers[i * NR_ + r];
    float s  = __fdividef(0.5f, sg * sg) + 1e-8f;
#pragma unroll
    for (int row = 0; row < 8; row++) {
      float d = Xs[row][i] - c;
      acc[row] = fmaf(d * s, d, acc[row]);
    }
  }
#pragma unroll
  for (int row = 0; row < 8; row++) pre[h][row][r] = acc[row];
  __syncthreads();
  int wv = tid >> 6, lane = tid & 63;
  float v0 = pre[0][wv][lane]      + pre[1][wv][lane]      + pre[2][wv][lane]      + pre[3][wv][lane];
  float v1 = pre[0][wv][lane + 64] + pre[1][wv][lane + 64] + pre[2][wv][lane + 64] + pre[3][wv][lane + 64];
  v0 *= -(1.f / 256.f);
  v1 *= -(1.f / 256.f);
  float m = fmaxf(v0, v1);
  for (int st = 32; st; st >>= 1) m = fmaxf(m, __shfl_xor(m, st));
  float e0 = __expf(v0 - m), e1 = __expf(v1 - m);
  float s = e0 + e1;
  for (int st = 32; st; st >>= 1) s += __shfl_xor(s, st);
  float invs = 1.f / s;
  float f0 = e0 * invs, f1 = e1 * invs;
  int b = b0 + wv;
  frs[(size_t)b * 128 + lane]      = f0;
  frs[(size_t)b * 128 + 64 + lane] = f1;
  float q = f0 * f0 + f1 * f1;
  for (int st = 32; st; st >>= 1) q += __shfl_xor(q, st);
  float sx = 0.f, sx2 = 0.f;
#pragma unroll
  for (int j = 0; j < 4; j++) {
    float x = Xs[wv][lane * 4 + j];
    sx += x; sx2 = fmaf(x, x, sx2);
  }
  for (int st = 32; st; st >>= 1) { sx += __shfl_xor(sx, st); sx2 += __shfl_xor(sx2, st); }
  if (lane == 0) {
    float mu  = (sx + 1.f) / (float)D_;
    float msq = q * (sx2 + 1.f) / (float)D_;
    float var = msq - mu * mu;
    float rs  = rsqrtf(var + 1e-5f);
    rstdO[b] = rs;
    murO[b]  = mu * rs;
  }
}

// ================= Kernel B: G/Bb finalize — 64 blocks (one per o), coalesced.
__global__ __launch_bounds__(256) void reduce_kernel(
    const float* __restrict__ W, const float* __restrict__ gamma,
    const float* __restrict__ beta, const float* __restrict__ bias,
    const float* __restrict__ Gpart, const float* __restrict__ Bpart,
    float* __restrict__ G, float* __restrict__ Bb) {
  int o = blockIdx.x, t = threadIdx.x;
  __shared__ float rg[256], rb[256];
  float gs = 0.f, bs = 0.f;
  for (int j = t; j < 1024; j += 256) {     // coalesced: Gpart[o][j]
    gs += Gpart[(size_t)o * 1024 + j];
    bs += Bpart[(size_t)o * 1024 + j];
  }
  if (t < 128) {                            // tail: contiguous over t
    int d = XP_ + t;
    float wt = W[(size_t)o * D_ + d];
    gs += wt * gamma[d];
    bs += wt * beta[d];
  }
  rg[t] = gs; rb[t] = bs;
  __syncthreads();
  for (int st = 128; st > 0; st >>= 1) {
    if (t < st) { rg[t] += rg[t + st]; rb[t] += rb[t + st]; }
    __syncthreads();
  }
  if (t == 0) { G[o] = rg[0]; Bb[o] = rb[0] + bias[o]; }
}

// ================= Kernel C: MFMA GEMM, LDS dbuf via global_load_lds.
// 512 blocks, bt-MINOR: bt = id&31, ks = id>>5 (ks-slices of one bt co-XCD).
// Each block stores Spart[bt][ks] = rstd*(S+T_ks) (plain stores, deterministic),
// bumps cnt[bt]; the block drawing old==15 sums the 16 slices + affine -> out.
__global__ __launch_bounds__(256) void gemm_kernel(
    const unsigned short* __restrict__ Xbf, const unsigned short* __restrict__ Bpack,
    const float* __restrict__ frs, const float* __restrict__ rstd,
    const float* __restrict__ Wtail, const float* __restrict__ G,
    const float* __restrict__ Bb, const float* __restrict__ mur,
    float* __restrict__ Spart, int* __restrict__ cnt,
    float* __restrict__ out) {
  __shared__ unsigned short Blds[2][16384];   // 2 x 32KB
  __shared__ float frs_s[64][9];
  __shared__ float Wt_s[8][64];
  __shared__ float rstd_s[64];
  __shared__ int sdone;
  int tid = threadIdx.x;

  int bt = blockIdx.x & 31, ks = blockIdx.x >> 5;
  int lane = tid & 63, w = tid >> 6, wr = w & 1, wc = w >> 1;

  for (int idx = tid; idx < 64 * 8; idx += 256) {
    int row = idx >> 3, rr = idx & 7;
    frs_s[row][rr] = frs[(size_t)(bt * 64 + row) * NR_ + ks * 8 + rr];
  }
  for (int idx = tid; idx < 512; idx += 256) {      // coalesced 2KB
    int rr = idx >> 6, o = idx & 63;
    Wt_s[rr][o] = Wtail[(ks * 8 + rr) * 64 + o];
  }
  if (tid < 64) rstd_s[tid] = rstd[bt * 64 + tid];

  // X fragments in registers, reused across all 8 rules
  s16x8 xf[2][8];
  int browbase = bt * 64 + wr * 32;
#pragma unroll
  for (int rf = 0; rf < 2; rf++) {
    const unsigned short* xp = Xbf + (size_t)(browbase + rf * 16 + (lane & 15)) * 256 + (lane >> 4) * 8;
#pragma unroll
    for (int kc = 0; kc < 8; kc++)
      xf[rf][kc] = *(const s16x8*)(xp + kc * 32);
  }

  // stage rule 0 into buf 0 (32KB: 8 x 16B per thread, linear)
  const char* bbase = (const char*)Bpack + (size_t)ks * 8 * 32768;
  char* lbase = (char*)&Blds[0][0];
  {
#pragma unroll
    for (int p = 0; p < 8; p++)
      gload_lds16(bbase + tid * 16 + p * 4096, lbase + (tid >> 6) * 1024 + p * 4096);
  }
  __syncthreads();   // drains vmcnt(0): buf0 + LDS tables ready

  f32x4 S00 = {0.f,0.f,0.f,0.f}, S01 = S00, S10 = S00, S11 = S00;

  for (int rr = 0; rr < 8; rr++) {
    if (rr < 7) {    // issue next-rule stage before compute
      const char* src = bbase + (size_t)(rr + 1) * 32768;
      char* ldst = lbase + ((rr + 1) & 1) * 32768;
#pragma unroll
      for (int p = 0; p < 8; p++)
        gload_lds16(src + tid * 16 + p * 4096, ldst + (tid >> 6) * 1024 + p * 4096);
    }
    const unsigned short* bb = &Blds[rr & 1][0];
    f32x4 P00 = {0.f,0.f,0.f,0.f}, P01 = P00, P10 = P00, P11 = P00;
#pragma unroll
    for (int kc = 0; kc < 8; kc++) {
      s16x8 bf0 = *(const s16x8*)(bb + (size_t)((kc * 4 + wc * 2 + 0) * 64 + lane) * 8);
      s16x8 bf1 = *(const s16x8*)(bb + (size_t)((kc * 4 + wc * 2 + 1) * 64 + lane) * 8);
      P00 = __builtin_amdgcn_mfma_f32_16x16x32_bf16(xf[0][kc], bf0, P00, 0, 0, 0);
      P10 = __builtin_amdgcn_mfma_f32_16x16x32_bf16(xf[1][kc], bf0, P10, 0, 0, 0);
      P01 = __builtin_amdgcn_mfma_f32_16x16x32_bf16(xf[0][kc], bf1, P01, 0, 0, 0);
      P11 = __builtin_amdgcn_mfma_f32_16x16x32_bf16(xf[1][kc], bf1, P11, 0, 0, 0);
    }
#pragma unroll
    for (int q = 0; q < 4; q++) {
      float fv0 = frs_s[wr * 32 + 0  + (lane >> 4) * 4 + q][rr];
      float fv1 = frs_s[wr * 32 + 16 + (lane >> 4) * 4 + q][rr];
      S00[q] += fv0 * P00[q];  S01[q] += fv0 * P01[q];
      S10[q] += fv1 * P10[q];  S11[q] += fv1 * P11[q];
    }
    __syncthreads();   // next buffer staged
  }

  // tail GEMV + rstd scale -> plain stores into this block's Spart slice
  float* sp = Spart + ((size_t)bt * KSPLIT + ks) * 4096;
  int o0 = wc * 32 + (lane & 15);
#pragma unroll
  for (int q = 0; q < 4; q++) {
    int lr0 = wr * 32 + 0  + (lane >> 4) * 4 + q;
    int lr1 = lr0 + 16;
    float t00 = 0.f, t01 = 0.f, t10 = 0.f, t11 = 0.f;
#pragma unroll
    for (int rr = 0; rr < 8; rr++) {
      float f0 = frs_s[lr0][rr], f1 = frs_s[lr1][rr];
      t00 = fmaf(f0, Wt_s[rr][o0],      t00);
      t01 = fmaf(f0, Wt_s[rr][o0 + 16], t01);
      t10 = fmaf(f1, Wt_s[rr][o0],      t10);
      t11 = fmaf(f1, Wt_s[rr][o0 + 16], t11);
    }
    float r0 = rstd_s[lr0], r1 = rstd_s[lr1];
    sp[lr0 * 64 + o0]      = r0 * (S00[q] + t00);
    sp[lr0 * 64 + o0 + 16] = r0 * (S01[q] + t01);
    sp[lr1 * 64 + o0]      = r1 * (S10[q] + t10);
    sp[lr1 * 64 + o0 + 16] = r1 * (S11[q] + t11);
  }

  // completion protocol: last block per bt sums the 16 slices + affine
  __threadfence();                       // publish Spart slice (device scope)
  if (tid == 0) sdone = atomicAdd(&cnt[bt], 1);
  __syncthreads();
  if (sdone == KSPLIT - 1) {
    __threadfence();                     // acquire: see all other slices
    const float* spb = Spart + (size_t)bt * KSPLIT * 4096;
    for (int e = tid; e < 4096; e += 256) {
      float s = 0.f;
#pragma unroll
      for (int k2 = 0; k2 < KSPLIT; k2++) s += spb[k2 * 4096 + e];
      int row = bt * 64 + (e >> 6), o = e & 63;
      out[(size_t)row * OUT_ + o] = s + Bb[o] - mur[row] * G[o];
    }
  }
}

extern "C" void kernel_launch(void* const* d_in, const int* in_sizes, int n_in,
                              void* d_out, int out_size, void* d_ws, size_t ws_size,
                              hipStream_t stream) {
  const float* X       = (const float*)d_in[0];
  const float* centers = (const float*)d_in[1];
  const float* sigmas  = (const float*)d_in[2];
  const float* gamma   = (const float*)d_in[3];
  const float* beta    = (const float*)d_in[4];
  const float* W       = (const float*)d_in[5];
  const float* bias    = (const float*)d_in[6];
  float* out = (float*)d_out;

  char* ws = (char*)d_ws;
  float* rstd          = (float*)(ws);                     // 8 KB
  float* mur           = (float*)(ws + 8192);              // 8 KB
  float* frs           = (float*)(ws + 16384);             // 1 MB
  unsigned short* Xbf  = (unsigned short*)(ws + 1064960);  // 1 MB
  unsigned short* Bpack= (unsigned short*)(ws + 2113536);  // 4 MB
  float* Gpart         = (float*)(ws + 6307840);           // 256 KB ([64][1024])
  float* Bpart         = (float*)(ws + 6569984);           // 256 KB
  float* Wtail         = (float*)(ws + 6832128);           // 32 KB
  float* G             = (float*)(ws + 6864896);           // 256 B
  float* Bb            = (float*)(ws + 6865152);           // 256 B
  int*   cnt           = (int*)  (ws + 6865408);           // 128 B
  float* Spart         = (float*)(ws + 6865536);           // 8 MB (total ~14.6 MB)

  hipLaunchKernelGGL(prep_frs_kernel, dim3(512), dim3(512), 0, stream,
                     X, centers, sigmas, W, gamma, beta,
                     Bpack, Gpart, Bpart, Wtail, frs, rstd, mur, Xbf, cnt);
  hipLaunchKernelGGL(reduce_kernel, dim3(OUT_), dim3(256), 0, stream,
                     W, gamma, beta, bias, Gpart, Bpart, G, Bb);
  hipLaunchKernelGGL(gemm_kernel, dim3(512), dim3(256), 0, stream,
                     Xbf, Bpack, frs, rstd, Wtail, G, Bb, mur, Spart, cnt, out);
}

// Round 12
// 116.565 us; speedup vs baseline: 1.4020x; 1.4020x over previous
//
#include <hip/hip_runtime.h>

// PreHTSK fused, MFMA edition v9 — latency-hiding gemm: 1024 blocks (32-row tiles),
// half-rule (16 KB) double-buffer -> 4 blocks/CU (16 waves/CU, 2x R8's TLP).
// Epilogue = proven v6 structure: atomicAdd out (bt-minor, XCD-local), affine
// constant folded into ks==0 blocks, separate coalesced reduce_kernel for G/Bb.
// out[b,o] = rstd[b]*(S+T) + Bb[o] - mur[b]*G[o]
//   S = sum_r frs[b,r] * sum_i X[b,i]*gamma[r*256+i]*W[o,r*256+i]
//   T = sum_r frs[b,r] * Wtail[r][o]
// LN closed-form: mu=(Sx+1)/D, E[f^2]=Q*(Sx2+1)/D, Q=sum frs^2 (sum frs = 1).

#define B_    2048
#define IN_   256
#define NR_   128
#define OUT_  64
#define D_    32896
#define XP_   32768
#define KSPLIT 16   // rule-groups; 8 rules per gemm block

typedef short s16x8 __attribute__((ext_vector_type(8)));
typedef float f32x4 __attribute__((ext_vector_type(4)));

__device__ __forceinline__ unsigned short bfc(float f) {
  union { float f; unsigned int u; } v; v.f = f;
  unsigned int r = (v.u + 0x7fffu + ((v.u >> 16) & 1u)) >> 16;  // RNE
  return (unsigned short)r;
}

__device__ __forceinline__ void gload_lds16(const void* g, void* l) {
  __builtin_amdgcn_global_load_lds(
      (const __attribute__((address_space(1))) void*)g,
      (__attribute__((address_space(3))) void*)l, 16, 0, 0);
}

// ================= Kernel A (512 blocks, 512 thr):
//   0..255   pack: r = bid>>1, ic-half = bid&1. Bpack fragments (bf16 gamma*W),
//            Gpart/Bpart partials ([o][1024] transposed), Wtail (half==1).
//   256..511 frs: firing levels + softmax + LN stats + X->bf16.
__global__ __launch_bounds__(512) void prep_frs_kernel(
    const float* __restrict__ X, const float* __restrict__ centers,
    const float* __restrict__ sigmas, const float* __restrict__ W,
    const float* __restrict__ gamma, const float* __restrict__ beta,
    unsigned short* __restrict__ Bpack, float* __restrict__ Gpart,
    float* __restrict__ Bpart, float* __restrict__ Wtail,
    float* __restrict__ frs, float* __restrict__ rstdO,
    float* __restrict__ murO, unsigned short* __restrict__ Xbf,
    float* __restrict__ out) {
  __shared__ float Wlds[64][68];      // pack path
  __shared__ float Xs[8][256];        // frs path
  __shared__ float pre[4][8][128];
  int tid = threadIdx.x;

  if (blockIdx.x < 256) {             // ---- pack path
    int r = blockIdx.x >> 1, half = blockIdx.x & 1;
    int lane = tid & 63, w = tid >> 6;
    int kcl = w & 1, ct = w >> 1;     // wave handles (k-half, col-tile)
    int o_f = ct * 16 + (lane & 15);
    if (half == 1 && tid < 64) {      // Wtail[r][o] (scattered, 64 loads)
      int d = XP_ + r;
      Wtail[r * 64 + tid] = W[(size_t)tid * D_ + d] * gamma[d];
    }
    for (int ici = 0; ici < 2; ici++) {
      int ic = half * 2 + ici;
      // coalesced: W[o][r*256+ic*64 .. +64) -> Wlds[o][0..64)
      for (int v = tid; v < 1024; v += 512) {
        int o = v >> 4, c4 = v & 15;
        float4 x = *(const float4*)&W[(size_t)o * D_ + r * 256 + ic * 64 + c4 * 4];
        *(float4*)&Wlds[o][c4 * 4] = x;
      }
      __syncthreads();
      int kc = ic * 2 + kcl;
      int il = kcl * 32 + (lane >> 4) * 8;
      int dg = r * 256 + ic * 64 + il;
      float4 g0  = *(const float4*)&gamma[dg];
      float4 g1  = *(const float4*)&gamma[dg + 4];
      float4 be0 = *(const float4*)&beta[dg];
      float4 be1 = *(const float4*)&beta[dg + 4];
      float4 w0 = *(const float4*)&Wlds[o_f][il];
      float4 w1 = *(const float4*)&Wlds[o_f][il + 4];
      unsigned int u[4];
      u[0] = bfc(w0.x * g0.x) | ((unsigned int)bfc(w0.y * g0.y) << 16);
      u[1] = bfc(w0.z * g0.z) | ((unsigned int)bfc(w0.w * g0.w) << 16);
      u[2] = bfc(w1.x * g1.x) | ((unsigned int)bfc(w1.y * g1.y) << 16);
      u[3] = bfc(w1.z * g1.z) | ((unsigned int)bfc(w1.w * g1.w) << 16);
      int rb = r * 8 + kc;
      *(uint4*)&Bpack[((size_t)(rb * 4 + ct) * 64 + lane) * 8] = make_uint4(u[0], u[1], u[2], u[3]);
      float gs = w0.x*g0.x + w0.y*g0.y + w0.z*g0.z + w0.w*g0.w
               + w1.x*g1.x + w1.y*g1.y + w1.z*g1.z + w1.w*g1.w;
      float bs = w0.x*be0.x + w0.y*be0.y + w0.z*be0.z + w0.w*be0.w
               + w1.x*be1.x + w1.y*be1.y + w1.z*be1.z + w1.w*be1.w;
      gs += __shfl_xor(gs, 16); gs += __shfl_xor(gs, 32);
      bs += __shfl_xor(bs, 16); bs += __shfl_xor(bs, 32);
      if ((lane >> 4) == 0) {         // transposed: [o][rb] for coalesced reduce
        Gpart[(size_t)o_f * 1024 + rb] = gs;
        Bpart[(size_t)o_f * 1024 + rb] = bs;
      }
      __syncthreads();
    }
    return;
  }

  // ---- frs path
  int bt = blockIdx.x - 256;          // 0..255
  int b0 = bt * 8;
  {
    // zero this block's out slice: 8 rows x 64 = 512 floats = 128 float4
    if (tid < 128) {
      float4 z = {0.f, 0.f, 0.f, 0.f};
      ((float4*)out)[bt * 128 + tid] = z;
    }
    int row = tid >> 6, c4 = (tid & 63) * 4;
    float4 x = *(const float4*)&X[(size_t)(b0 + row) * 256 + c4];
    *(float4*)&Xs[row][c4] = x;
    uint2 p;
    p.x = bfc(x.x) | ((unsigned int)bfc(x.y) << 16);
    p.y = bfc(x.z) | ((unsigned int)bfc(x.w) << 16);
    *(uint2*)&Xbf[(size_t)(b0 + row) * 256 + c4] = p;
  }
  __syncthreads();
  int r = tid & 127, h = tid >> 7;
  float acc[8] = {0.f,0.f,0.f,0.f,0.f,0.f,0.f,0.f};
  int i0 = h * 64;
#pragma unroll 4
  for (int i = i0; i < i0 + 64; i++) {
    float sg = sigmas[i * NR_ + r];
    float c  = centers[i * NR_ + r];
    float s  = __fdividef(0.5f, sg * sg) + 1e-8f;
#pragma unroll
    for (int row = 0; row < 8; row++) {
      float d = Xs[row][i] - c;
      acc[row] = fmaf(d * s, d, acc[row]);
    }
  }
#pragma unroll
  for (int row = 0; row < 8; row++) pre[h][row][r] = acc[row];
  __syncthreads();
  int wv = tid >> 6, lane = tid & 63;
  float v0 = pre[0][wv][lane]      + pre[1][wv][lane]      + pre[2][wv][lane]      + pre[3][wv][lane];
  float v1 = pre[0][wv][lane + 64] + pre[1][wv][lane + 64] + pre[2][wv][lane + 64] + pre[3][wv][lane + 64];
  v0 *= -(1.f / 256.f);
  v1 *= -(1.f / 256.f);
  float m = fmaxf(v0, v1);
  for (int st = 32; st; st >>= 1) m = fmaxf(m, __shfl_xor(m, st));
  float e0 = __expf(v0 - m), e1 = __expf(v1 - m);
  float s = e0 + e1;
  for (int st = 32; st; st >>= 1) s += __shfl_xor(s, st);
  float invs = 1.f / s;
  float f0 = e0 * invs, f1 = e1 * invs;
  int b = b0 + wv;
  frs[(size_t)b * 128 + lane]      = f0;
  frs[(size_t)b * 128 + 64 + lane] = f1;
  float q = f0 * f0 + f1 * f1;
  for (int st = 32; st; st >>= 1) q += __shfl_xor(q, st);
  float sx = 0.f, sx2 = 0.f;
#pragma unroll
  for (int j = 0; j < 4; j++) {
    float x = Xs[wv][lane * 4 + j];
    sx += x; sx2 = fmaf(x, x, sx2);
  }
  for (int st = 32; st; st >>= 1) { sx += __shfl_xor(sx, st); sx2 += __shfl_xor(sx2, st); }
  if (lane == 0) {
    float mu  = (sx + 1.f) / (float)D_;
    float msq = q * (sx2 + 1.f) / (float)D_;
    float var = msq - mu * mu;
    float rs  = rsqrtf(var + 1e-5f);
    rstdO[b] = rs;
    murO[b]  = mu * rs;
  }
}

// ================= Kernel B: G/Bb finalize — 64 blocks (one per o), coalesced.
__global__ __launch_bounds__(256) void reduce_kernel(
    const float* __restrict__ W, const float* __restrict__ gamma,
    const float* __restrict__ beta, const float* __restrict__ bias,
    const float* __restrict__ Gpart, const float* __restrict__ Bpart,
    float* __restrict__ G, float* __restrict__ Bb) {
  int o = blockIdx.x, t = threadIdx.x;
  __shared__ float rg[256], rb[256];
  float gs = 0.f, bs = 0.f;
  for (int j = t; j < 1024; j += 256) {     // coalesced: Gpart[o][j]
    gs += Gpart[(size_t)o * 1024 + j];
    bs += Bpart[(size_t)o * 1024 + j];
  }
  if (t < 128) {                            // tail: contiguous over t
    int d = XP_ + t;
    float wt = W[(size_t)o * D_ + d];
    gs += wt * gamma[d];
    bs += wt * beta[d];
  }
  rg[t] = gs; rb[t] = bs;
  __syncthreads();
  for (int st = 128; st > 0; st >>= 1) {
    if (t < st) { rg[t] += rg[t + st]; rb[t] += rb[t + st]; }
    __syncthreads();
  }
  if (t == 0) { G[o] = rg[0]; Bb[o] = rb[0] + bias[o]; }
}

// ================= Kernel C: MFMA GEMM, half-rule (16 KB) LDS dbuf, 4 blocks/CU.
// 1024 blocks, bt-MINOR: bt = id&63 (32-row tile), ks = id>>6 (8 rules).
// 16 half-steps: stage 16 KB (kc quad) of next half while computing current.
// ks==0 blocks also add the affine constant Bb[o] - mur[b]*G[o].
__global__ __launch_bounds__(256) void gemm_kernel(
    const unsigned short* __restrict__ Xbf, const unsigned short* __restrict__ Bpack,
    const float* __restrict__ frs, const float* __restrict__ rstd,
    const float* __restrict__ Wtail, const float* __restrict__ G,
    const float* __restrict__ Bb, const float* __restrict__ mur,
    float* __restrict__ out) {
  __shared__ unsigned short Blds[2][8192];    // 2 x 16KB
  __shared__ float frs_s[32][9];
  __shared__ float Wt_s[8][64];
  __shared__ float rstd_s[32];
  __shared__ float G_s[64], Bb_s[64], mur_s[32];
  int tid = threadIdx.x;

  int bt = blockIdx.x & 63, ks = blockIdx.x >> 6;
  int lane = tid & 63, w = tid >> 6, wr = w & 1, wc = w >> 1;

  if (tid < 256) {   // frs_s: 32 rows x 8 rules, one entry per thread
    int row = tid >> 3, rr = tid & 7;
    frs_s[row][rr] = frs[(size_t)(bt * 32 + row) * NR_ + ks * 8 + rr];
  }
  for (int idx = tid; idx < 512; idx += 256) {      // coalesced 2KB
    int rr = idx >> 6, o = idx & 63;
    Wt_s[rr][o] = Wtail[(ks * 8 + rr) * 64 + o];
  }
  if (tid < 32) {
    rstd_s[tid] = rstd[bt * 32 + tid];
    if (ks == 0) mur_s[tid] = mur[bt * 32 + tid];
  }
  if (ks == 0 && tid < 64) {
    G_s[tid]  = G[tid];
    Bb_s[tid] = Bb[tid];
  }

  // X fragments in registers (16 rows x 256 k), reused across all 8 rules
  s16x8 xf[8];
  int browbase = bt * 32 + wr * 16;
  {
    const unsigned short* xp = Xbf + (size_t)(browbase + (lane & 15)) * 256 + (lane >> 4) * 8;
#pragma unroll
    for (int kc = 0; kc < 8; kc++)
      xf[kc] = *(const s16x8*)(xp + kc * 32);
  }

  // stage half 0 (rule 0, kc 0..3) into buf 0: 16KB = 4 x 16B per thread
  const char* bbase = (const char*)Bpack + (size_t)ks * 8 * 32768;
  char* lbase = (char*)&Blds[0][0];
  {
#pragma unroll
    for (int p = 0; p < 4; p++)
      gload_lds16(bbase + tid * 16 + p * 4096, lbase + w * 1024 + p * 4096);
  }
  __syncthreads();   // drains vmcnt(0): buf0 + LDS tables ready

  f32x4 S0 = {0.f,0.f,0.f,0.f}, S1 = S0;
  f32x4 P0 = S0, P1 = S0;

  for (int h = 0; h < 16; h++) {            // h = rule*2 + khalf
    if (h < 15) {    // stage next half into the other buffer
      const char* src = bbase + (size_t)(h + 1) * 16384;
      char* ldst = lbase + ((h + 1) & 1) * 16384;
#pragma unroll
      for (int p = 0; p < 4; p++)
        gload_lds16(src + tid * 16 + p * 4096, ldst + w * 1024 + p * 4096);
    }
    const unsigned short* bb = &Blds[h & 1][0];
    int kbase = (h & 1) * 4;                // global kc offset of this half
#pragma unroll
    for (int kcl = 0; kcl < 4; kcl++) {
      s16x8 bf0 = *(const s16x8*)(bb + (size_t)((kcl * 4 + wc * 2 + 0) * 64 + lane) * 8);
      s16x8 bf1 = *(const s16x8*)(bb + (size_t)((kcl * 4 + wc * 2 + 1) * 64 + lane) * 8);
      P0 = __builtin_amdgcn_mfma_f32_16x16x32_bf16(xf[kbase + kcl], bf0, P0, 0, 0, 0);
      P1 = __builtin_amdgcn_mfma_f32_16x16x32_bf16(xf[kbase + kcl], bf1, P1, 0, 0, 0);
    }
    if (h & 1) {     // rule complete: fold with f32 frs, reset P
      int rr = h >> 1;
#pragma unroll
      for (int q = 0; q < 4; q++) {
        float fv = frs_s[wr * 16 + (lane >> 4) * 4 + q][rr];
        S0[q] += fv * P0[q];  S1[q] += fv * P1[q];
        P0[q] = 0.f; P1[q] = 0.f;
      }
    }
    __syncthreads();   // next buffer staged
  }

  // tail GEMV + rstd scale (+ affine constant on ks==0) + atomic accumulate
  int o0 = wc * 32 + (lane & 15);
#pragma unroll
  for (int q = 0; q < 4; q++) {
    int lr = wr * 16 + (lane >> 4) * 4 + q;
    float t0 = 0.f, t1 = 0.f;
#pragma unroll
    for (int rr = 0; rr < 8; rr++) {
      float f = frs_s[lr][rr];
      t0 = fmaf(f, Wt_s[rr][o0],      t0);
      t1 = fmaf(f, Wt_s[rr][o0 + 16], t1);
    }
    float r0 = rstd_s[lr];
    float c0 = 0.f, c1 = 0.f;
    if (ks == 0) {
      c0 = Bb_s[o0]      - mur_s[lr] * G_s[o0];
      c1 = Bb_s[o0 + 16] - mur_s[lr] * G_s[o0 + 16];
    }
    size_t base = (size_t)(bt * 32 + lr) * OUT_;
    atomicAdd(&out[base + o0],      r0 * (S0[q] + t0) + c0);
    atomicAdd(&out[base + o0 + 16], r0 * (S1[q] + t1) + c1);
  }
}

extern "C" void kernel_launch(void* const* d_in, const int* in_sizes, int n_in,
                              void* d_out, int out_size, void* d_ws, size_t ws_size,
                              hipStream_t stream) {
  const float* X       = (const float*)d_in[0];
  const float* centers = (const float*)d_in[1];
  const float* sigmas  = (const float*)d_in[2];
  const float* gamma   = (const float*)d_in[3];
  const float* beta    = (const float*)d_in[4];
  const float* W       = (const float*)d_in[5];
  const float* bias    = (const float*)d_in[6];
  float* out = (float*)d_out;

  char* ws = (char*)d_ws;
  float* rstd          = (float*)(ws);                     // 8 KB
  float* mur           = (float*)(ws + 8192);              // 8 KB
  float* frs           = (float*)(ws + 16384);             // 1 MB
  unsigned short* Xbf  = (unsigned short*)(ws + 1064960);  // 1 MB
  unsigned short* Bpack= (unsigned short*)(ws + 2113536);  // 4 MB
  float* Gpart         = (float*)(ws + 6307840);           // 256 KB ([64][1024])
  float* Bpart         = (float*)(ws + 6569984);           // 256 KB
  float* Wtail         = (float*)(ws + 6832128);           // 32 KB
  float* G             = (float*)(ws + 6864896);           // 256 B
  float* Bb            = (float*)(ws + 6865152);           // 256 B (total ~6.9 MB)

  hipLaunchKernelGGL(prep_frs_kernel, dim3(512), dim3(512), 0, stream,
                     X, centers, sigmas, W, gamma, beta,
                     Bpack, Gpart, Bpart, Wtail, frs, rstd, mur, Xbf, out);
  hipLaunchKernelGGL(reduce_kernel, dim3(OUT_), dim3(256), 0, stream,
                     W, gamma, beta, bias, Gpart, Bpart, G, Bb);
  hipLaunchKernelGGL(gemm_kernel, dim3(1024), dim3(256), 0, stream,
                     Xbf, Bpack, frs, rstd, Wtail, G, Bb, mur, out);
}